// Round 1
// baseline (2826.038 us; speedup 1.0000x reference)
//
#include <hip/hip_runtime.h>

#define F 128          // feature width
#define BR 64          // rows per GEMM block tile
#define KC 32          // k-chunk for GEMM staging

// ---------------------------------------------------------------------------
// Kernel 1: edge scatter-add.  agg[dst[e]][:] += h[src[e]][:]
// One edge handled by 32 consecutive lanes, each lane owns 4 floats (float4).
// unsafeAtomicAdd -> HW global_atomic_add_f32 (no CAS loop).
// ---------------------------------------------------------------------------
__global__ void scatter_add_kernel(const float* __restrict__ h,
                                   const int* __restrict__ src,
                                   const int* __restrict__ dst,
                                   float* __restrict__ agg,
                                   long total /* n_edges * 32 */) {
    long stride = (long)gridDim.x * blockDim.x;
    for (long i = (long)blockIdx.x * blockDim.x + threadIdx.x; i < total; i += stride) {
        int e    = (int)(i >> 5);
        int lane = (int)(i & 31);
        int s = src[e];
        int d = dst[e];
        float4 v = *(const float4*)(h + (long)s * F + (lane << 2));
        float* o = agg + (long)d * F + (lane << 2);
        unsafeAtomicAdd(o + 0, v.x);
        unsafeAtomicAdd(o + 1, v.y);
        unsafeAtomicAdd(o + 2, v.z);
        unsafeAtomicAdd(o + 3, v.w);
    }
}

// ---------------------------------------------------------------------------
// Kernel 2: out = relu(agg @ W.T + b), computed IN PLACE on d_out.
// Block tile: 64 rows x 128 cols, 256 threads, per-thread micro-tile 4x8
// (4 rows x {4 cols at tx*4, 4 cols at 64+tx*4} -> conflict-free b128 LDS reads).
// A and W staged transposed in LDS per 32-wide k-chunk.
// In-place is safe: each block only reads/writes its own 64 rows, and all
// reads (into LDS) complete before the epilogue stores.
// ---------------------------------------------------------------------------
__global__ __launch_bounds__(256) void gemm_bias_relu_inplace(
        float* __restrict__ out,          // [n][128]; in: agg, out: result
        const float* __restrict__ W,      // [128][128] row-major (W[j][k])
        const float* __restrict__ bias,   // [128]
        int n_rows) {
    __shared__ __align__(16) float a_t[KC][BR + 4];   // a_t[k][r], pad->bank spread
    __shared__ __align__(16) float w_t[KC][F + 4];    // w_t[k][j]

    const int tid = threadIdx.x;
    const int tx = tid & 15;          // 16 col groups
    const int ty = tid >> 4;          // 16 row groups
    const int row0 = blockIdx.x * BR;

    float acc[4][8];
    #pragma unroll
    for (int i = 0; i < 4; ++i)
        #pragma unroll
        for (int j = 0; j < 8; ++j) acc[i][j] = 0.f;

    for (int kc = 0; kc < F; kc += KC) {
        // ---- stage A chunk transposed: 64 rows x 32 k  (512 float4 loads) ----
        #pragma unroll
        for (int p = 0; p < 2; ++p) {
            int q  = tid + p * 256;      // 0..511
            int r  = q >> 3;             // 0..63
            int kq = q & 7;              // 0..7 (float4 within chunk)
            int row = row0 + r;
            float4 v = make_float4(0.f, 0.f, 0.f, 0.f);
            if (row < n_rows)
                v = *(const float4*)(out + (long)row * F + kc + (kq << 2));
            a_t[kq * 4 + 0][r] = v.x;
            a_t[kq * 4 + 1][r] = v.y;
            a_t[kq * 4 + 2][r] = v.z;
            a_t[kq * 4 + 3][r] = v.w;
        }
        // ---- stage W chunk transposed: 128 j x 32 k (1024 float4 loads) ----
        #pragma unroll
        for (int p = 0; p < 4; ++p) {
            int q  = tid + p * 256;      // 0..1023
            int j  = q >> 3;             // 0..127
            int kq = q & 7;
            float4 v = *(const float4*)(W + (long)j * F + kc + (kq << 2));
            w_t[kq * 4 + 0][j] = v.x;
            w_t[kq * 4 + 1][j] = v.y;
            w_t[kq * 4 + 2][j] = v.z;
            w_t[kq * 4 + 3][j] = v.w;
        }
        __syncthreads();

        // ---- compute: 32 k-steps, 3x ds_read_b128 + 32 v_fmac per step ----
        #pragma unroll
        for (int k = 0; k < KC; ++k) {
            float4 av = *(const float4*)&a_t[k][ty << 2];
            float4 w0 = *(const float4*)&w_t[k][tx << 2];
            float4 w1 = *(const float4*)&w_t[k][64 + (tx << 2)];
            float a4[4] = {av.x, av.y, av.z, av.w};
            float wv[8] = {w0.x, w0.y, w0.z, w0.w, w1.x, w1.y, w1.z, w1.w};
            #pragma unroll
            for (int i = 0; i < 4; ++i)
                #pragma unroll
                for (int j = 0; j < 8; ++j)
                    acc[i][j] += a4[i] * wv[j];
        }
        __syncthreads();
    }

    // ---- epilogue: bias + relu, coalesced float4 stores ----
    float4 b0 = *(const float4*)(bias + (tx << 2));
    float4 b1 = *(const float4*)(bias + 64 + (tx << 2));
    #pragma unroll
    for (int i = 0; i < 4; ++i) {
        int row = row0 + (ty << 2) + i;
        if (row < n_rows) {
            float4 r0, r1;
            r0.x = fmaxf(acc[i][0] + b0.x, 0.f);
            r0.y = fmaxf(acc[i][1] + b0.y, 0.f);
            r0.z = fmaxf(acc[i][2] + b0.z, 0.f);
            r0.w = fmaxf(acc[i][3] + b0.w, 0.f);
            r1.x = fmaxf(acc[i][4] + b1.x, 0.f);
            r1.y = fmaxf(acc[i][5] + b1.y, 0.f);
            r1.z = fmaxf(acc[i][6] + b1.z, 0.f);
            r1.w = fmaxf(acc[i][7] + b1.w, 0.f);
            *(float4*)(out + (long)row * F + (tx << 2)) = r0;
            *(float4*)(out + (long)row * F + 64 + (tx << 2)) = r1;
        }
    }
}

extern "C" void kernel_launch(void* const* d_in, const int* in_sizes, int n_in,
                              void* d_out, int out_size, void* d_ws, size_t ws_size,
                              hipStream_t stream) {
    const float* h   = (const float*)d_in[0];
    const int*   src = (const int*)d_in[1];
    const int*   dst = (const int*)d_in[2];
    const float* W   = (const float*)d_in[3];
    const float* b   = (const float*)d_in[4];
    float* out = (float*)d_out;

    const int n_nodes = in_sizes[0] / F;
    const int n_edges = in_sizes[1];

    // agg accumulates in-place in d_out; it is re-poisoned before every launch,
    // so zero it here (async memset is graph-capture safe).
    hipMemsetAsync(out, 0, (size_t)out_size * sizeof(float), stream);

    // Edge scatter: 32 lanes/edge, grid-stride.
    const long total = (long)n_edges * 32;
    scatter_add_kernel<<<16384, 256, 0, stream>>>(h, src, dst, out, total);

    // Fused GEMM + bias + relu, in place on d_out.
    const int gblocks = (n_nodes + BR - 1) / BR;
    gemm_bias_relu_inplace<<<gblocks, 256, 0, stream>>>(out, W, b, n_nodes);
}

// Round 2
// 379.000 us; speedup vs baseline: 7.4566x; 7.4566x over previous
//
#include <hip/hip_runtime.h>

#define F    128        // feature width
#define MAXD 64         // slot capacity per node (== wave size; Poisson(16) max deg ~45)
#define BR   64         // rows per GEMM block tile
#define KC   32         // k-chunk for GEMM staging

// ---------------------------------------------------------------------------
// Kernel A: build per-destination edge lists in workspace.
//   cnt[d]  = degree counter (int atomics, L2-resident, low contention)
//   slots[d*MAXD + pos] = src node id
// Overflow (pos >= MAXD, never fires for this dataset): atomically add h[src]
// straight into out[d] — out is pre-zeroed, gather adds it back in.
// ---------------------------------------------------------------------------
__global__ void build_slots_kernel(const int* __restrict__ src,
                                   const int* __restrict__ dst,
                                   const float* __restrict__ h,
                                   int* __restrict__ cnt,
                                   int* __restrict__ slots,
                                   float* __restrict__ out,
                                   int n_edges) {
    int stride = gridDim.x * blockDim.x;
    for (int e = blockIdx.x * blockDim.x + threadIdx.x; e < n_edges; e += stride) {
        int s = src[e];
        int d = dst[e];
        int pos = atomicAdd(&cnt[d], 1);
        if (pos < MAXD) {
            slots[(long)d * MAXD + pos] = s;
        } else {                       // cold path, correctness only
            const float* hr = h + (long)s * F;
            float* o = out + (long)d * F;
            for (int k = 0; k < F; ++k) unsafeAtomicAdd(o + k, hr[k]);
        }
    }
}

// ---------------------------------------------------------------------------
// Kernel B: gather-aggregate. One 64-lane wave per node.
// All 64 slot ids loaded in ONE coalesced b32 load (MAXD == 64 == wave size),
// broadcast per-edge via __shfl. Each lane owns 2 floats (float2) of the row.
// No atomics; each out row written exactly once.
// ---------------------------------------------------------------------------
__global__ __launch_bounds__(256) void gather_agg_kernel(
        const float* __restrict__ h,
        const int* __restrict__ cnt,
        const int* __restrict__ slots,
        float* __restrict__ out,
        int n_nodes) {
    const int lane = threadIdx.x & 63;
    const int wave_in_blk = threadIdx.x >> 6;              // 0..3
    int n = blockIdx.x * 4 + wave_in_blk;                  // one node per wave
    if (n >= n_nodes) return;

    const int c = cnt[n];
    const int d = min(c, MAXD);

    // one coalesced load grabs this node's entire slot list
    int sv = slots[(long)n * MAXD + lane];                 // valid for lane < d

    float2 acc = make_float2(0.f, 0.f);
    int i = 0;
    for (; i + 1 < d; i += 2) {                            // 2 loads in flight
        int s0 = __shfl(sv, i);
        int s1 = __shfl(sv, i + 1);
        float2 v0 = *(const float2*)(h + (long)s0 * F + (lane << 1));
        float2 v1 = *(const float2*)(h + (long)s1 * F + (lane << 1));
        acc.x += v0.x; acc.y += v0.y;
        acc.x += v1.x; acc.y += v1.y;
    }
    if (i < d) {
        int s0 = __shfl(sv, i);
        float2 v0 = *(const float2*)(h + (long)s0 * F + (lane << 1));
        acc.x += v0.x; acc.y += v0.y;
    }

    float* o = out + (long)n * F + (lane << 1);
    if (c > MAXD) {                                        // overflow contributions
        float2 prev = *(const float2*)o;
        acc.x += prev.x; acc.y += prev.y;
    }
    *(float2*)o = acc;
}

// ---------------------------------------------------------------------------
// Fallback (ws too small): round-1 direct atomic scatter.
// ---------------------------------------------------------------------------
__global__ void scatter_add_kernel(const float* __restrict__ h,
                                   const int* __restrict__ src,
                                   const int* __restrict__ dst,
                                   float* __restrict__ agg,
                                   long total) {
    long stride = (long)gridDim.x * blockDim.x;
    for (long i = (long)blockIdx.x * blockDim.x + threadIdx.x; i < total; i += stride) {
        int e    = (int)(i >> 5);
        int lane = (int)(i & 31);
        int s = src[e];
        int d = dst[e];
        float4 v = *(const float4*)(h + (long)s * F + (lane << 2));
        float* o = agg + (long)d * F + (lane << 2);
        unsafeAtomicAdd(o + 0, v.x);
        unsafeAtomicAdd(o + 1, v.y);
        unsafeAtomicAdd(o + 2, v.z);
        unsafeAtomicAdd(o + 3, v.w);
    }
}

// ---------------------------------------------------------------------------
// Kernel C: out = relu(agg @ W.T + b), in place on d_out. (unchanged from R1)
// ---------------------------------------------------------------------------
__global__ __launch_bounds__(256) void gemm_bias_relu_inplace(
        float* __restrict__ out,
        const float* __restrict__ W,
        const float* __restrict__ bias,
        int n_rows) {
    __shared__ __align__(16) float a_t[KC][BR + 4];
    __shared__ __align__(16) float w_t[KC][F + 4];

    const int tid = threadIdx.x;
    const int tx = tid & 15;
    const int ty = tid >> 4;
    const int row0 = blockIdx.x * BR;

    float acc[4][8];
    #pragma unroll
    for (int i = 0; i < 4; ++i)
        #pragma unroll
        for (int j = 0; j < 8; ++j) acc[i][j] = 0.f;

    for (int kc = 0; kc < F; kc += KC) {
        #pragma unroll
        for (int p = 0; p < 2; ++p) {
            int q  = tid + p * 256;
            int r  = q >> 3;
            int kq = q & 7;
            int row = row0 + r;
            float4 v = make_float4(0.f, 0.f, 0.f, 0.f);
            if (row < n_rows)
                v = *(const float4*)(out + (long)row * F + kc + (kq << 2));
            a_t[kq * 4 + 0][r] = v.x;
            a_t[kq * 4 + 1][r] = v.y;
            a_t[kq * 4 + 2][r] = v.z;
            a_t[kq * 4 + 3][r] = v.w;
        }
        #pragma unroll
        for (int p = 0; p < 4; ++p) {
            int q  = tid + p * 256;
            int j  = q >> 3;
            int kq = q & 7;
            float4 v = *(const float4*)(W + (long)j * F + kc + (kq << 2));
            w_t[kq * 4 + 0][j] = v.x;
            w_t[kq * 4 + 1][j] = v.y;
            w_t[kq * 4 + 2][j] = v.z;
            w_t[kq * 4 + 3][j] = v.w;
        }
        __syncthreads();

        #pragma unroll
        for (int k = 0; k < KC; ++k) {
            float4 av = *(const float4*)&a_t[k][ty << 2];
            float4 w0 = *(const float4*)&w_t[k][tx << 2];
            float4 w1 = *(const float4*)&w_t[k][64 + (tx << 2)];
            float a4[4] = {av.x, av.y, av.z, av.w};
            float wv[8] = {w0.x, w0.y, w0.z, w0.w, w1.x, w1.y, w1.z, w1.w};
            #pragma unroll
            for (int i = 0; i < 4; ++i)
                #pragma unroll
                for (int j = 0; j < 8; ++j)
                    acc[i][j] += a4[i] * wv[j];
        }
        __syncthreads();
    }

    float4 b0 = *(const float4*)(bias + (tx << 2));
    float4 b1 = *(const float4*)(bias + 64 + (tx << 2));
    #pragma unroll
    for (int i = 0; i < 4; ++i) {
        int row = row0 + (ty << 2) + i;
        if (row < n_rows) {
            float4 r0, r1;
            r0.x = fmaxf(acc[i][0] + b0.x, 0.f);
            r0.y = fmaxf(acc[i][1] + b0.y, 0.f);
            r0.z = fmaxf(acc[i][2] + b0.z, 0.f);
            r0.w = fmaxf(acc[i][3] + b0.w, 0.f);
            r1.x = fmaxf(acc[i][4] + b1.x, 0.f);
            r1.y = fmaxf(acc[i][5] + b1.y, 0.f);
            r1.z = fmaxf(acc[i][6] + b1.z, 0.f);
            r1.w = fmaxf(acc[i][7] + b1.w, 0.f);
            *(float4*)(out + (long)row * F + (tx << 2)) = r0;
            *(float4*)(out + (long)row * F + 64 + (tx << 2)) = r1;
        }
    }
}

extern "C" void kernel_launch(void* const* d_in, const int* in_sizes, int n_in,
                              void* d_out, int out_size, void* d_ws, size_t ws_size,
                              hipStream_t stream) {
    const float* h   = (const float*)d_in[0];
    const int*   src = (const int*)d_in[1];
    const int*   dst = (const int*)d_in[2];
    const float* W   = (const float*)d_in[3];
    const float* b   = (const float*)d_in[4];
    float* out = (float*)d_out;

    const int n_nodes = in_sizes[0] / F;
    const int n_edges = in_sizes[1];

    const size_t need = (size_t)n_nodes * sizeof(int)                 // cnt
                      + (size_t)n_nodes * MAXD * sizeof(int);         // slots

    if (ws_size >= need) {
        int* cnt   = (int*)d_ws;
        int* slots = cnt + n_nodes;

        // cnt must be zero; out must be zero only for the (never-taken)
        // overflow atomic path — keep both for unconditional correctness.
        hipMemsetAsync(cnt, 0, (size_t)n_nodes * sizeof(int), stream);
        hipMemsetAsync(out, 0, (size_t)out_size * sizeof(float), stream);

        build_slots_kernel<<<(n_edges + 255) / 256, 256, 0, stream>>>(
            src, dst, h, cnt, slots, out, n_edges);

        // one wave per node, 4 waves per block
        gather_agg_kernel<<<(n_nodes + 3) / 4, 256, 0, stream>>>(
            h, cnt, slots, out, n_nodes);
    } else {
        // fallback: direct atomic scatter (round-1 path)
        hipMemsetAsync(out, 0, (size_t)out_size * sizeof(float), stream);
        scatter_add_kernel<<<16384, 256, 0, stream>>>(
            h, src, dst, out, (long)n_edges * 32);
    }

    const int gblocks = (n_nodes + BR - 1) / BR;
    gemm_bias_relu_inplace<<<gblocks, 256, 0, stream>>>(out, W, b, n_nodes);
}

// Round 3
// 359.819 us; speedup vs baseline: 7.8541x; 1.0533x over previous
//
#include <hip/hip_runtime.h>

#define F    128        // feature width
#define MAXD 64         // slot capacity per node (== wave size; Poisson(16) max deg ~45)
#define BR   64         // rows per GEMM block tile
#define KC   32         // k-chunk for GEMM staging
#define EPB  8          // edges per thread in build (ILP batching)

// ---------------------------------------------------------------------------
// Kernel 0: fp32 -> bf16 (RNE) conversion of h into workspace.
// ---------------------------------------------------------------------------
__device__ __forceinline__ unsigned short f32_to_bf16_rne(float x) {
    unsigned u = __float_as_uint(x);
    u += 0x7fffu + ((u >> 16) & 1u);     // round to nearest even (no NaN in data)
    return (unsigned short)(u >> 16);
}

__global__ __launch_bounds__(256) void conv_bf16_kernel(
        const float* __restrict__ h, unsigned short* __restrict__ hb, int n4) {
    int stride = gridDim.x * blockDim.x;
    for (int i = blockIdx.x * blockDim.x + threadIdx.x; i < n4; i += stride) {
        float4 v = *(const float4*)(h + 4 * (long)i);
        ushort4 o;
        o.x = f32_to_bf16_rne(v.x);
        o.y = f32_to_bf16_rne(v.y);
        o.z = f32_to_bf16_rne(v.z);
        o.w = f32_to_bf16_rne(v.w);
        *(ushort4*)(hb + 4 * (long)i) = o;
    }
}

// ---------------------------------------------------------------------------
// Kernel A: build per-destination edge lists. 8 edges per thread so 8
// independent atomic->store chains are in flight (round-2 version was
// 1 edge/thread and pure latency-bound: VALUBusy 0.5%, 25 G ops/s).
// Overflow (never fires for Poisson(16) degrees): atomic-add h row into
// pre-zeroed out; gather merges it back.
// ---------------------------------------------------------------------------
__global__ __launch_bounds__(256) void build_slots_kernel(
        const int* __restrict__ src,
        const int* __restrict__ dst,
        const float* __restrict__ h,
        int* __restrict__ cnt,
        int* __restrict__ slots,
        float* __restrict__ out,
        int n_edges) {
    const int T = gridDim.x * blockDim.x;
    const int t = blockIdx.x * blockDim.x + threadIdx.x;

    for (long g = 0; g < n_edges; g += (long)EPB * T) {
        int  s[EPB], d[EPB], p[EPB];
        bool ok[EPB];
        #pragma unroll
        for (int j = 0; j < EPB; ++j) {           // coalesced batched loads
            long idx = g + (long)j * T + t;
            ok[j] = idx < n_edges;
            if (ok[j]) { s[j] = src[idx]; d[j] = dst[idx]; }
        }
        #pragma unroll
        for (int j = 0; j < EPB; ++j)             // 8 independent atomics
            if (ok[j]) p[j] = atomicAdd(&cnt[d[j]], 1);
        #pragma unroll
        for (int j = 0; j < EPB; ++j) {           // 8 independent stores
            if (!ok[j]) continue;
            if (p[j] < MAXD) {
                slots[(long)d[j] * MAXD + p[j]] = s[j];
            } else {                              // cold correctness path
                const float* hr = h + (long)s[j] * F;
                float* o = out + (long)d[j] * F;
                for (int k = 0; k < F; ++k) unsafeAtomicAdd(o + k, hr[k]);
            }
        }
    }
}

// ---------------------------------------------------------------------------
// Kernel B (tier 1): gather-aggregate from bf16 h. One 64-lane wave per node;
// slot list loaded in one coalesced b32; rows broadcast via __shfl; each lane
// owns 2 features packed in one uint (2 bf16). fp32 accumulation.
// ---------------------------------------------------------------------------
__global__ __launch_bounds__(256) void gather_agg_bf16_kernel(
        const unsigned short* __restrict__ hb,
        const int* __restrict__ cnt,
        const int* __restrict__ slots,
        float* __restrict__ out,
        int n_nodes) {
    const int lane = threadIdx.x & 63;
    int n = blockIdx.x * 4 + (threadIdx.x >> 6);
    if (n >= n_nodes) return;

    const int c = cnt[n];
    const int d = min(c, MAXD);
    int sv = slots[(long)n * MAXD + lane];

    float ax = 0.f, ay = 0.f;
    int i = 0;
    for (; i + 3 < d; i += 4) {                   // 4 row-loads in flight
        int s0 = __shfl(sv, i);
        int s1 = __shfl(sv, i + 1);
        int s2 = __shfl(sv, i + 2);
        int s3 = __shfl(sv, i + 3);
        unsigned v0 = *(const unsigned*)(hb + (long)s0 * F + (lane << 1));
        unsigned v1 = *(const unsigned*)(hb + (long)s1 * F + (lane << 1));
        unsigned v2 = *(const unsigned*)(hb + (long)s2 * F + (lane << 1));
        unsigned v3 = *(const unsigned*)(hb + (long)s3 * F + (lane << 1));
        ax += __uint_as_float(v0 << 16) + __uint_as_float(v1 << 16)
            + __uint_as_float(v2 << 16) + __uint_as_float(v3 << 16);
        ay += __uint_as_float(v0 & 0xffff0000u) + __uint_as_float(v1 & 0xffff0000u)
            + __uint_as_float(v2 & 0xffff0000u) + __uint_as_float(v3 & 0xffff0000u);
    }
    for (; i < d; ++i) {
        int s0 = __shfl(sv, i);
        unsigned v0 = *(const unsigned*)(hb + (long)s0 * F + (lane << 1));
        ax += __uint_as_float(v0 << 16);
        ay += __uint_as_float(v0 & 0xffff0000u);
    }

    float* o = out + (long)n * F + (lane << 1);
    if (c > MAXD) { float2 prev = *(const float2*)o; ax += prev.x; ay += prev.y; }
    *(float2*)o = make_float2(ax, ay);
}

// ---------------------------------------------------------------------------
// Kernel B (tier 2): fp32 gather (round-2 version), used if ws can't hold hb.
// ---------------------------------------------------------------------------
__global__ __launch_bounds__(256) void gather_agg_kernel(
        const float* __restrict__ h,
        const int* __restrict__ cnt,
        const int* __restrict__ slots,
        float* __restrict__ out,
        int n_nodes) {
    const int lane = threadIdx.x & 63;
    int n = blockIdx.x * 4 + (threadIdx.x >> 6);
    if (n >= n_nodes) return;

    const int c = cnt[n];
    const int d = min(c, MAXD);
    int sv = slots[(long)n * MAXD + lane];

    float2 acc = make_float2(0.f, 0.f);
    int i = 0;
    for (; i + 1 < d; i += 2) {
        int s0 = __shfl(sv, i);
        int s1 = __shfl(sv, i + 1);
        float2 v0 = *(const float2*)(h + (long)s0 * F + (lane << 1));
        float2 v1 = *(const float2*)(h + (long)s1 * F + (lane << 1));
        acc.x += v0.x + v1.x; acc.y += v0.y + v1.y;
    }
    if (i < d) {
        int s0 = __shfl(sv, i);
        float2 v0 = *(const float2*)(h + (long)s0 * F + (lane << 1));
        acc.x += v0.x; acc.y += v0.y;
    }

    float* o = out + (long)n * F + (lane << 1);
    if (c > MAXD) { float2 prev = *(const float2*)o; acc.x += prev.x; acc.y += prev.y; }
    *(float2*)o = acc;
}

// ---------------------------------------------------------------------------
// Tier 3 fallback: direct atomic scatter.
// ---------------------------------------------------------------------------
__global__ void scatter_add_kernel(const float* __restrict__ h,
                                   const int* __restrict__ src,
                                   const int* __restrict__ dst,
                                   float* __restrict__ agg,
                                   long total) {
    long stride = (long)gridDim.x * blockDim.x;
    for (long i = (long)blockIdx.x * blockDim.x + threadIdx.x; i < total; i += stride) {
        int e    = (int)(i >> 5);
        int lane = (int)(i & 31);
        int s = src[e];
        int d = dst[e];
        float4 v = *(const float4*)(h + (long)s * F + (lane << 2));
        float* o = agg + (long)d * F + (lane << 2);
        unsafeAtomicAdd(o + 0, v.x);
        unsafeAtomicAdd(o + 1, v.y);
        unsafeAtomicAdd(o + 2, v.z);
        unsafeAtomicAdd(o + 3, v.w);
    }
}

// ---------------------------------------------------------------------------
// Kernel C: out = relu(agg @ W.T + b), in place on d_out. (unchanged)
// ---------------------------------------------------------------------------
__global__ __launch_bounds__(256) void gemm_bias_relu_inplace(
        float* __restrict__ out,
        const float* __restrict__ W,
        const float* __restrict__ bias,
        int n_rows) {
    __shared__ __align__(16) float a_t[KC][BR + 4];
    __shared__ __align__(16) float w_t[KC][F + 4];

    const int tid = threadIdx.x;
    const int tx = tid & 15;
    const int ty = tid >> 4;
    const int row0 = blockIdx.x * BR;

    float acc[4][8];
    #pragma unroll
    for (int i = 0; i < 4; ++i)
        #pragma unroll
        for (int j = 0; j < 8; ++j) acc[i][j] = 0.f;

    for (int kc = 0; kc < F; kc += KC) {
        #pragma unroll
        for (int p = 0; p < 2; ++p) {
            int q  = tid + p * 256;
            int r  = q >> 3;
            int kq = q & 7;
            int row = row0 + r;
            float4 v = make_float4(0.f, 0.f, 0.f, 0.f);
            if (row < n_rows)
                v = *(const float4*)(out + (long)row * F + kc + (kq << 2));
            a_t[kq * 4 + 0][r] = v.x;
            a_t[kq * 4 + 1][r] = v.y;
            a_t[kq * 4 + 2][r] = v.z;
            a_t[kq * 4 + 3][r] = v.w;
        }
        #pragma unroll
        for (int p = 0; p < 4; ++p) {
            int q  = tid + p * 256;
            int j  = q >> 3;
            int kq = q & 7;
            float4 v = *(const float4*)(W + (long)j * F + kc + (kq << 2));
            w_t[kq * 4 + 0][j] = v.x;
            w_t[kq * 4 + 1][j] = v.y;
            w_t[kq * 4 + 2][j] = v.z;
            w_t[kq * 4 + 3][j] = v.w;
        }
        __syncthreads();

        #pragma unroll
        for (int k = 0; k < KC; ++k) {
            float4 av = *(const float4*)&a_t[k][ty << 2];
            float4 w0 = *(const float4*)&w_t[k][tx << 2];
            float4 w1 = *(const float4*)&w_t[k][64 + (tx << 2)];
            float a4[4] = {av.x, av.y, av.z, av.w};
            float wv[8] = {w0.x, w0.y, w0.z, w0.w, w1.x, w1.y, w1.z, w1.w};
            #pragma unroll
            for (int i = 0; i < 4; ++i)
                #pragma unroll
                for (int j = 0; j < 8; ++j)
                    acc[i][j] += a4[i] * wv[j];
        }
        __syncthreads();
    }

    float4 b0 = *(const float4*)(bias + (tx << 2));
    float4 b1 = *(const float4*)(bias + 64 + (tx << 2));
    #pragma unroll
    for (int i = 0; i < 4; ++i) {
        int row = row0 + (ty << 2) + i;
        if (row < n_rows) {
            float4 r0, r1;
            r0.x = fmaxf(acc[i][0] + b0.x, 0.f);
            r0.y = fmaxf(acc[i][1] + b0.y, 0.f);
            r0.z = fmaxf(acc[i][2] + b0.z, 0.f);
            r0.w = fmaxf(acc[i][3] + b0.w, 0.f);
            r1.x = fmaxf(acc[i][4] + b1.x, 0.f);
            r1.y = fmaxf(acc[i][5] + b1.y, 0.f);
            r1.z = fmaxf(acc[i][6] + b1.z, 0.f);
            r1.w = fmaxf(acc[i][7] + b1.w, 0.f);
            *(float4*)(out + (long)row * F + (tx << 2)) = r0;
            *(float4*)(out + (long)row * F + 64 + (tx << 2)) = r1;
        }
    }
}

extern "C" void kernel_launch(void* const* d_in, const int* in_sizes, int n_in,
                              void* d_out, int out_size, void* d_ws, size_t ws_size,
                              hipStream_t stream) {
    const float* h   = (const float*)d_in[0];
    const int*   src = (const int*)d_in[1];
    const int*   dst = (const int*)d_in[2];
    const float* W   = (const float*)d_in[3];
    const float* b   = (const float*)d_in[4];
    float* out = (float*)d_out;

    const int n_nodes = in_sizes[0] / F;
    const int n_edges = in_sizes[1];

    const size_t need_t2 = (size_t)n_nodes * sizeof(int)                 // cnt
                         + (size_t)n_nodes * MAXD * sizeof(int);         // slots
    const size_t need_t1 = need_t2
                         + (size_t)n_nodes * F * sizeof(unsigned short); // hb

    const int build_grid = (n_edges + 256 * EPB - 1) / (256 * EPB);

    if (ws_size >= need_t2) {
        int* cnt   = (int*)d_ws;
        int* slots = cnt + n_nodes;
        unsigned short* hb = (unsigned short*)(slots + (size_t)n_nodes * MAXD);

        hipMemsetAsync(cnt, 0, (size_t)n_nodes * sizeof(int), stream);
        hipMemsetAsync(out, 0, (size_t)out_size * sizeof(float), stream);

        const bool tier1 = ws_size >= need_t1;
        if (tier1) {
            const int n4 = n_nodes * F / 4;
            conv_bf16_kernel<<<2048, 256, 0, stream>>>(h, hb, n4);
        }

        build_slots_kernel<<<build_grid, 256, 0, stream>>>(
            src, dst, h, cnt, slots, out, n_edges);

        if (tier1)
            gather_agg_bf16_kernel<<<(n_nodes + 3) / 4, 256, 0, stream>>>(
                hb, cnt, slots, out, n_nodes);
        else
            gather_agg_kernel<<<(n_nodes + 3) / 4, 256, 0, stream>>>(
                h, cnt, slots, out, n_nodes);
    } else {
        hipMemsetAsync(out, 0, (size_t)out_size * sizeof(float), stream);
        scatter_add_kernel<<<16384, 256, 0, stream>>>(
            h, src, dst, out, (long)n_edges * 32);
    }

    const int gblocks = (n_nodes + BR - 1) / BR;
    gemm_bias_relu_inplace<<<gblocks, 256, 0, stream>>>(out, W, b, n_nodes);
}